// Round 5
// baseline (211.401 us; speedup 1.0000x reference)
//
#include <hip/hip_runtime.h>
#include <hip/hip_bf16.h>

// retina_polar2: log-polar glimpse sampling + 10x10 avg-pool
// x:        [64, 3, 512, 512] f32
// l_t_prev: [64, 2]           f32
// grid_2d:  [320, 640, 2]     f32  (gx, gy)
// out:      [64, 3, 32, 64]   f32
//
// Latency-chain-bound gather. Round-5 structure:
//  - block = (b, pair p, theta-seg): thread does windows ho=p and ho=31-p
//    (balanced: pair cost <= 2x mean), 2048 blocks x 5 waves.
//  - per window: ONE grid-wait (10 float2 coalesced), then two gather
//    batches of 60 (3 channels x 5 rows x 4 taps) -> 3 waitcnt rounds
//    per window instead of 4+.
//  - __launch_bounds__(320,4): VGPR<=128 -> 4 waves/SIMD residency.

#define B_    64
#define C_    3
#define HI_   512
#define WI_   512
#define HOUT_ 32
#define WOUT_ 64
#define UFR_  10
#define UFT_  10
#define WUP_  (WOUT_ * UFT_)   // 640
#define BLK_  320

__global__ __launch_bounds__(BLK_, 4) void retina_polar_kernel(
    const float* __restrict__ x,
    const float* __restrict__ lt,
    const float* __restrict__ grid,
    float* __restrict__ out)
{
    const int bid = blockIdx.x;
    const int b   = bid >> 5;          // / 32
    const int p   = (bid >> 1) & 15;   // window pair id
    const int seg = bid & 1;           // theta half
    const int tid = threadIdx.x;
    const int wu  = seg * BLK_ + tid;  // theta column
    const int wol = tid / UFT_;        // 0..31 local output column

    __shared__ float acc[C_][2][32];   // [c][k][wol]

    if (tid < C_ * 2 * 32) ((float*)acc)[tid] = 0.0f;
    __syncthreads();

    const float lx = lt[b * 2 + 0];
    const float ly = lt[b * 2 + 1];
    const float* __restrict__ xb = x + (size_t)b * C_ * HI_ * WI_;

    #pragma unroll 1
    for (int k = 0; k < 2; ++k) {
        const int w   = k ? (31 - p) : p;
        const int hu0 = w * UFR_;

        // ---- one coalesced grid batch: 10 float2 (one waitcnt) ----
        float gxv[UFR_], gyv[UFR_];
        #pragma unroll
        for (int rr = 0; rr < UFR_; ++rr) {
            const float2 g = *reinterpret_cast<const float2*>(
                grid + ((size_t)(hu0 + rr) * WUP_ + wu) * 2);
            gxv[rr] = g.x + lx;
            gyv[rr] = g.y + ly;
        }

        // ---- coords: packed a00 | dx1<<18 | dy1<<19 ----
        int   ap [UFR_];
        float wxv[UFR_], wyv[UFR_];
        #pragma unroll
        for (int rr = 0; rr < UFR_; ++rr) {
            float ix = ((gxv[rr] + 1.0f) * (float)WI_ - 1.0f) * 0.5f;
            float iy = ((gyv[rr] + 1.0f) * (float)HI_ - 1.0f) * 0.5f;
            ix = fminf(fmaxf(ix, 0.0f), (float)(WI_ - 1));
            iy = fminf(fmaxf(iy, 0.0f), (float)(HI_ - 1));
            const float x0f = floorf(ix);
            const float y0f = floorf(iy);
            const int x0 = (int)x0f;
            const int y0 = (int)y0f;
            const int dx1 = min(x0 + 1, WI_ - 1) - x0;   // 0/1
            const int dy1 = min(y0 + 1, HI_ - 1) - y0;   // 0/1
            ap [rr] = (y0 * WI_ + x0) | (dx1 << 18) | (dy1 << 19);
            wxv[rr] = ix - x0f;
            wyv[rr] = iy - y0f;
        }

        float s[C_] = {0.0f, 0.0f, 0.0f};

        // ---- two gather batches of 60 (3ch x 5rr x 4taps) ----
        #pragma unroll
        for (int hh = 0; hh < 2; ++hh) {
            float v00[C_][5], v01[C_][5], v10[C_][5], v11[C_][5];
            #pragma unroll
            for (int c = 0; c < C_; ++c) {
                const float* __restrict__ xc = xb + (size_t)c * HI_ * WI_;
                #pragma unroll
                for (int j = 0; j < 5; ++j) {
                    const int pk  = ap[hh * 5 + j];
                    const int A   = pk & 0x3FFFF;
                    const int dxo = (pk >> 18) & 1;
                    const int dyo = (pk >> 10) & 512;  // bit19 -> +512
                    v00[c][j] = xc[A];
                    v01[c][j] = xc[A + dxo];
                    v10[c][j] = xc[A + dyo];
                    v11[c][j] = xc[A + dxo + dyo];
                }
            }
            #pragma unroll
            for (int c = 0; c < C_; ++c) {
                #pragma unroll
                for (int j = 0; j < 5; ++j) {
                    const int rr = hh * 5 + j;
                    const float w11 = wxv[rr] * wyv[rr];
                    const float w10 = wyv[rr] - w11;
                    const float w01 = wxv[rr] - w11;
                    const float w00 = 1.0f - wxv[rr] - wyv[rr] + w11;
                    s[c] += v00[c][j] * w00 + v01[c][j] * w01
                          + v10[c][j] * w10 + v11[c][j] * w11;
                }
            }
        }

        atomicAdd(&acc[0][k][wol], s[0]);
        atomicAdd(&acc[1][k][wol], s[1]);
        atomicAdd(&acc[2][k][wol], s[2]);
    }
    __syncthreads();

    // ---- write out: 3 * 2 windows * 32 cols = 192 values ----
    if (tid < C_ * 2 * 32) {
        const int c   = tid >> 6;
        const int rem = tid & 63;
        const int kk  = rem >> 5;
        const int wl  = rem & 31;
        const int w   = kk ? (31 - p) : p;
        out[(((size_t)b * C_ + c) * HOUT_ + w) * WOUT_ + seg * 32 + wl] =
            acc[c][kk][wl] * 0.01f;
    }
}

extern "C" void kernel_launch(void* const* d_in, const int* in_sizes, int n_in,
                              void* d_out, int out_size, void* d_ws, size_t ws_size,
                              hipStream_t stream)
{
    const float* x    = (const float*)d_in[0];
    const float* lt   = (const float*)d_in[1];
    const float* grid = (const float*)d_in[2];
    float* out        = (float*)d_out;

    retina_polar_kernel<<<dim3(B_ * 16 * 2), dim3(BLK_), 0, stream>>>(x, lt, grid, out);
}

// Round 6
// 115.667 us; speedup vs baseline: 1.8277x; 1.8277x over previous
//
#include <hip/hip_runtime.h>
#include <hip/hip_bf16.h>

// retina_polar2: log-polar glimpse sampling + 10x10 avg-pool
// x:        [64, 3, 512, 512] f32
// l_t_prev: [64, 2]           f32
// grid_2d:  [320, 640, 2]     f32  (gx, gy)
// out:      [64, 3, 32, 64]   f32
//
// VMEM-address-throughput-bound gather (~1 lane-address/cy/CU wall).
// Round-6: halve address count — the two x-taps of each bilinear row
// always fit in ONE float4 loaded at xe = min(x0 & ~1, 508) (8B-aligned,
// never crosses the image row). 2 dwordx4 per sample instead of 4 dword.
// Extraction = per-lane 4:1 muxes (v_cndmask), VALU has headroom.
// Geometry identical to round 4 (balanced 4-window spread, unroll 1).

#define B_    64
#define C_    3
#define HI_   512
#define WI_   512
#define HOUT_ 32
#define WOUT_ 64
#define UFR_  10
#define UFT_  10
#define WUP_  (WOUT_ * UFT_)   // 640
#define WEDGE_ 80
#define BLK_  320

__device__ __forceinline__ float sel4(float4 f, int k) {
    // 4:1 mux -> 3 v_cndmask
    const float a = (k & 2) ? f.z : f.x;
    const float b = (k & 2) ? f.w : f.y;
    return (k & 1) ? b : a;
}

__global__ __launch_bounds__(BLK_) void retina_polar_kernel(
    const float* __restrict__ x,
    const float* __restrict__ lt,
    const float* __restrict__ grid,
    float* __restrict__ out)
{
    const int bid   = blockIdx.x;
    const int b     = bid >> 4;
    const int wedge = (bid >> 1) & 7;
    const int h     = bid & 1;
    const int tid   = threadIdx.x;
    const int tl    = tid % WEDGE_;
    const int rg    = tid / WEDGE_;
    const int wu    = wedge * WEDGE_ + tl;
    const int wol   = tl / UFT_;          // 0..7

    __shared__ float acc[C_][16][8];

    for (int i = tid; i < C_ * 16 * 8; i += BLK_)
        ((float*)acc)[i] = 0.0f;
    __syncthreads();

    const float lx = lt[b * 2 + 0];
    const float ly = lt[b * 2 + 1];
    const float* __restrict__ xb = x + (size_t)b * C_ * HI_ * WI_;

    #pragma unroll 1
    for (int k = 0; k < 4; ++k) {
        const int slot = rg + 4 * k;        // 0..15
        const int w    = h + 2 * slot;      // ho
        const int hu0  = w * UFR_;

        // ---- coords: packed Ae | q<<18 | dx<<20 | dy<<21 ----
        // Ae = y0*512 + xe, xe = min(x0 & ~1, 508)  (8B-aligned pair base)
        int   ap [UFR_];
        float wxv[UFR_], wyv[UFR_];
        #pragma unroll
        for (int rr = 0; rr < UFR_; ++rr) {
            const float2 g = *reinterpret_cast<const float2*>(
                grid + ((size_t)(hu0 + rr) * WUP_ + wu) * 2);
            float ix = ((g.x + lx + 1.0f) * (float)WI_ - 1.0f) * 0.5f;
            float iy = ((g.y + ly + 1.0f) * (float)HI_ - 1.0f) * 0.5f;
            ix = fminf(fmaxf(ix, 0.0f), (float)(WI_ - 1));
            iy = fminf(fmaxf(iy, 0.0f), (float)(HI_ - 1));
            const float x0f = floorf(ix);
            const float y0f = floorf(iy);
            const int x0 = (int)x0f;
            const int y0 = (int)y0f;
            const int dx1 = min(x0 + 1, WI_ - 1) - x0;   // 0/1
            const int dy1 = min(y0 + 1, HI_ - 1) - y0;   // 0/1
            const int xe  = min(x0 & ~1, WI_ - 4);       // 8B-aligned, in-row
            const int q   = x0 - xe;                     // 0..3
            ap [rr] = (y0 * WI_ + xe) | (q << 18) | (dx1 << 20) | (dy1 << 21);
            wxv[rr] = ix - x0f;
            wyv[rr] = iy - y0f;
        }

        // ---- per-channel: 2 float4 loads per sample, batches of 5 ----
        float s[C_];
        #pragma unroll
        for (int c = 0; c < C_; ++c) {
            const float* __restrict__ xc = xb + (size_t)c * HI_ * WI_;
            float a = 0.0f;
            #pragma unroll
            for (int hh = 0; hh < 2; ++hh) {
                float4 f0[5], f1[5];
                #pragma unroll
                for (int j = 0; j < 5; ++j) {
                    const int pk  = ap[hh * 5 + j];
                    const int Ae  = pk & 0x3FFFF;
                    const int dyo = (pk >> 12) & 512;   // bit21 -> +512
                    f0[j] = *reinterpret_cast<const float4*>(xc + Ae);
                    f1[j] = *reinterpret_cast<const float4*>(xc + Ae + dyo);
                }
                #pragma unroll
                for (int j = 0; j < 5; ++j) {
                    const int rr = hh * 5 + j;
                    const int pk = ap[rr];
                    const int q  = (pk >> 18) & 3;
                    const int i1 = q + ((pk >> 20) & 1);   // 0..3
                    const float v00 = sel4(f0[j], q);
                    const float v01 = sel4(f0[j], i1);
                    const float v10 = sel4(f1[j], q);
                    const float v11 = sel4(f1[j], i1);
                    const float w11 = wxv[rr] * wyv[rr];
                    const float w10 = wyv[rr] - w11;
                    const float w01 = wxv[rr] - w11;
                    const float w00 = 1.0f - wxv[rr] - wyv[rr] + w11;
                    a += v00 * w00 + v01 * w01 + v10 * w10 + v11 * w11;
                }
            }
            s[c] = a;
        }

        atomicAdd(&acc[0][slot][wol], s[0]);
        atomicAdd(&acc[1][slot][wol], s[1]);
        atomicAdd(&acc[2][slot][wol], s[2]);
    }
    __syncthreads();

    for (int i = tid; i < C_ * 16 * 8; i += BLK_) {
        const int c    = i >> 7;
        const int rem  = i & 127;
        const int slot = rem >> 3;
        const int wl   = rem & 7;
        const int w    = h + 2 * slot;
        out[(((size_t)b * C_ + c) * HOUT_ + w) * WOUT_ + wedge * 8 + wl] =
            acc[c][slot][wl] * 0.01f;
    }
}

extern "C" void kernel_launch(void* const* d_in, const int* in_sizes, int n_in,
                              void* d_out, int out_size, void* d_ws, size_t ws_size,
                              hipStream_t stream)
{
    const float* x    = (const float*)d_in[0];
    const float* lt   = (const float*)d_in[1];
    const float* grid = (const float*)d_in[2];
    float* out        = (float*)d_out;

    retina_polar_kernel<<<dim3(B_ * 8 * 2), dim3(BLK_), 0, stream>>>(x, lt, grid, out);
}